// Round 1
// baseline (362.483 us; speedup 1.0000x reference)
//
#include <hip/hip_runtime.h>

#define Hdim 128
#define Tlen 512
#define BT 8      // batch rows per block -> grid 256 = 1 block/CU
#define STR 136   // padded LDS row stride in fp16 elems (272B = 17x16B)

typedef __attribute__((ext_vector_type(8))) _Float16 f16x8;
typedef __attribute__((ext_vector_type(2))) _Float16 f16x2;
typedef __attribute__((ext_vector_type(4))) float f32x4;

__device__ __forceinline__ f32x4 mfma_f16(f16x8 a, f16x8 b, f32x4 c) {
  return __builtin_amdgcn_mfma_f32_16x16x32_f16(a, b, c, 0, 0, 0);
}
// dest lane i (within 16-lane DPP row): i>=8 gets src lane i-8's v; i<8 keeps
// `old` (bound_ctrl=false). Rebalances C-regs 2,3 onto the duplicate lanes.
__device__ __forceinline__ float dpp_shl8(float old, float v) {
  int r = __builtin_amdgcn_update_dpp(__builtin_bit_cast(int, old),
                                      __builtin_bit_cast(int, v),
                                      0x108 /*row_shl:8*/, 0xF, 0xF, false);
  return __builtin_bit_cast(float, r);
}

// R11 = R10 bit-exact + static wave-priority de-phasing.
// Counter evidence (R10): VALUBusy 54.6 + MfmaUtil 34.8 = 89.4% (additive,
// no pipe overlap) with only ~11% stall -> the 2 waves/SIMD are phase-locked
// by the per-step barrier: both do MFMA together (~590 cyc/SIMD), then both
// serialize on the trans unit (~924 cyc: 40 trans insts/SIMD/step, bit-exact
// locked). Fix: seed persistent priority asymmetry — waves 0-3 (one per SIMD
// under round-robin wave->SIMD placement) run at prio 1 for the whole kernel.
// Lead wave clears each contended pipe first; trail wave's MFMA phase slides
// under lead's trans phase. Target schedule per SIMD: M_lead -> {V_lead ||
// M_trail} -> V_trail ~= 1150-1250 cyc/step vs 1693 now. No FP changes: the
// 512-step trajectory stays bit-identical (absmax must remain 0.0078125).
// Structure (R5 residual +25%, R6 BT=4 +73%, R7 16-wave +45% all worse):
// 8 waves, BT=8, wave w owns M-tiles {w+8s} = gates i,f,g,o of units
// 16w..16w+15; B cols 8-15 duplicate 0-7 (bank-broadcast); h fp16 RNE;
// c fp32-resident; one barrier/step; W pre-scaled -log2e (i,f,o) / +2log2e (g).
__global__ __launch_bounds__(512, 2)
void lstm_disc_kernel(const float* __restrict__ x, const float* __restrict__ hx0,
                      const float* __restrict__ cx0, const float* __restrict__ W_ih,
                      const float* __restrict__ W_hh, const float* __restrict__ b_ih,
                      const float* __restrict__ b_hh, const float* __restrict__ W_mlp,
                      const float* __restrict__ b_mlp, float* __restrict__ out) {
  __shared__ _Float16 hbuf0[BT * STR];
  __shared__ _Float16 hbuf1[BT * STR];

  const int tid  = threadIdx.x;
  const int w    = tid >> 6;          // wave 0..7
  const int lane = tid & 63;
  const int l16  = lane & 15;         // B col n / A row m
  const int quad = lane >> 4;         // 0..3
  const int b0   = blockIdx.x * BT;
  const int bb   = l16 & 7;           // batch row (cols 8-15 duplicate 0-7)
  const bool hi  = (l16 < 8);
  const int uoff = quad * 4 + (hi ? 0 : 2);   // in-wave unit offset (even)
  const int ub   = 16 * w + uoff;             // first owned unit

  // ---- A fragments: W_hh pre-scaled; x/bias terms in final cell layout ----
  f16x8 wh[4][4];
  float wihG[4][2], biasG[4][2];
#pragma unroll
  for (int s = 0; s < 4; s++) {
    const float sc = (s == 2) ? 2.88539008f : -1.44269504f;  // g : i,f,o
    const int j = 16 * w + 128 * s + l16;       // gate row, type s
#pragma unroll
    for (int q = 0; q < 4; q++) {
      const float* p = W_hh + j * Hdim + q * 32 + quad * 8;
      f16x8 f;
#pragma unroll
      for (int e = 0; e < 8; e++) f[e] = (_Float16)(p[e] * sc);
      wh[s][q] = f;
    }
#pragma unroll
    for (int r2 = 0; r2 < 2; r2++) {
      const int j2 = 16 * w + 128 * s + uoff + r2;
      wihG[s][r2]  = W_ih[j2] * sc;
      biasG[s][r2] = (b_ih[j2] + b_hh[j2]) * sc;
    }
  }

  // ---- h0 -> LDS rows 0-7, fp16 RNE ----
  for (int i = tid; i < BT * Hdim; i += 512) {
    const int b = i >> 7, k = i & 127;
    hbuf0[b * STR + k] = (_Float16)hx0[(b0 + b) * Hdim + k];
  }

  // ---- c0: lane owns units ub, ub+1 of batch bb ----
  float c[2] = {cx0[(b0 + bb) * Hdim + ub], cx0[(b0 + bb) * Hdim + ub + 1]};

  const float* xp = x + (b0 + bb) * Tlen;
  float xv[4] = {xp[0], xp[1], xp[2], xp[3]};

  __syncthreads();

  // Persistent priority asymmetry: one lead wave per SIMD (round-robin
  // wave->SIMD placement pairs w and w+4 on SIMD w%4). Scheduling-only;
  // no FP op is added/removed/reordered within a wave.
  if (w < 4) __builtin_amdgcn_s_setprio(1);

  const f32x4 Z = {0.0f, 0.0f, 0.0f, 0.0f};

  auto step = [&](const _Float16* __restrict__ src, _Float16* __restrict__ dst,
                  float xcur) {
    // B frags: B[k=quad*8+e][n=l16], col n = batch bb (8-15 broadcast-dup)
    f16x8 bfrag[4];
#pragma unroll
    for (int q = 0; q < 4; q++)
      bfrag[q] = *(const f16x8*)&src[bb * STR + q * 32 + quad * 8];

    // four independent 4-deep MFMA chains (gate types i,f,g,o)
    f32x4 a[4];
#pragma unroll
    for (int s = 0; s < 4; s++) a[s] = mfma_f16(wh[s][0], bfrag[0], Z);
#pragma unroll
    for (int q = 1; q < 4; q++)
#pragma unroll
      for (int s = 0; s < 4; s++) a[s] = mfma_f16(wh[s][q], bfrag[q], a[s]);

    // rebalance: lanes >=8 take regs 2,3 from lane-8; add bias + x*W_ih
    float G[4][2];
#pragma unroll
    for (int s = 0; s < 4; s++)
#pragma unroll
      for (int r2 = 0; r2 < 2; r2++) {
        float g = dpp_shl8(a[s][r2], a[s][2 + r2]);
        G[s][r2] = __builtin_fmaf(xcur, wihG[s][r2], g + biasG[s][r2]);
      }

    // LSTM pointwise, 2 cells/lane, gates pre-scaled (no mul before exp2)
    float hv[2];
#pragma unroll
    for (int r2 = 0; r2 < 2; r2++) {
      float iv = __builtin_amdgcn_rcpf(1.0f + __builtin_amdgcn_exp2f(G[0][r2]));
      float fv = __builtin_amdgcn_rcpf(1.0f + __builtin_amdgcn_exp2f(G[1][r2]));
      float gv = 1.0f - 2.0f * __builtin_amdgcn_rcpf(
                              __builtin_amdgcn_exp2f(G[2][r2]) + 1.0f);
      float ov = __builtin_amdgcn_rcpf(1.0f + __builtin_amdgcn_exp2f(G[3][r2]));
      float cn = __builtin_fmaf(fv, c[r2], iv * gv);
      c[r2] = cn;
      float tc = 1.0f - 2.0f * __builtin_amdgcn_rcpf(
                              __builtin_amdgcn_exp2f(cn * 2.88539008f) + 1.0f);
      hv[r2] = ov * tc;
    }
    f16x2 hp;
    hp[0] = (_Float16)hv[0];   // RNE
    hp[1] = (_Float16)hv[1];
    *(f16x2*)&dst[bb * STR + ub] = hp;

    __syncthreads();
  };

  for (int t = 0; t < Tlen; t += 4) {
    const int tn = t + 4;
    float xa = xp[(tn     < Tlen) ? tn     : Tlen - 1];
    float xb = xp[(tn + 1 < Tlen) ? tn + 1 : Tlen - 1];
    float xc = xp[(tn + 2 < Tlen) ? tn + 2 : Tlen - 1];
    float xd = xp[(tn + 3 < Tlen) ? tn + 3 : Tlen - 1];
    step(hbuf0, hbuf1, xv[0]);
    step(hbuf1, hbuf0, xv[1]);
    step(hbuf0, hbuf1, xv[2]);
    step(hbuf1, hbuf0, xv[3]);
    xv[0] = xa; xv[1] = xb; xv[2] = xc; xv[3] = xd;
  }

  // ---- epilogue: out[b] = sigmoid(h . W_mlp + b_mlp); final h in hbuf0 ----
  if (w < 4) __builtin_amdgcn_s_setprio(0);
  if (tid < BT) {
    float s = 0.0f;
#pragma unroll 8
    for (int k = 0; k < Hdim; k++)
      s += (float)hbuf0[tid * STR + k] * W_mlp[k];
    out[b0 + tid] = __builtin_amdgcn_rcpf(
        1.0f + __builtin_amdgcn_exp2f((s + b_mlp[0]) * -1.44269504f));
  }
}

extern "C" void kernel_launch(void* const* d_in, const int* in_sizes, int n_in,
                              void* d_out, int out_size, void* d_ws, size_t ws_size,
                              hipStream_t stream) {
  const float* x     = (const float*)d_in[0];
  const float* hx0   = (const float*)d_in[1];
  const float* cx0   = (const float*)d_in[2];
  const float* W_ih  = (const float*)d_in[3];
  const float* W_hh  = (const float*)d_in[4];
  const float* b_ih  = (const float*)d_in[5];
  const float* b_hh  = (const float*)d_in[6];
  const float* W_mlp = (const float*)d_in[7];
  const float* b_mlp = (const float*)d_in[8];
  float* out = (float*)d_out;

  const int B = in_sizes[1] / Hdim;   // hx0 is [B, H]
  dim3 grid(B / BT), block(512);
  lstm_disc_kernel<<<grid, block, 0, stream>>>(x, hx0, cx0, W_ih, W_hh, b_ih,
                                               b_hh, W_mlp, b_mlp, out);
}